// Round 12
// baseline (194.279 us; speedup 1.0000x reference)
//
#include <hip/hip_runtime.h>

#define NT   512
#define NBLK 2048   // B/16 : 2 batch-tiles of 64 per block

typedef _Float16 half8 __attribute__((ext_vector_type(8)));
typedef _Float16 half4 __attribute__((ext_vector_type(4)));
typedef unsigned short us8 __attribute__((ext_vector_type(8)));
typedef float    f32x4 __attribute__((ext_vector_type(4)));

// ---- LDS float offsets (44.5 KB -> 3 blocks/CU) ----
#define L_UV   0          // [2][2 half][32 col][64] f : U/V f16 swz (32KB)
#define L_AH   0          // overlays UV: [2][64][32] f Ah f16 swz (16KB, dead after phase-1)
#define L_DPH  8192       // [2][32][32] f : dpH f16 swz (8KB)
#define S_BD1  10240      // 128
#define S_BD2  10368      // 128
#define S_C0   10496      // 64
#define S_C1   10560      // 64
#define S_SP   10624      // [2][2][128] partial sums
#define LDS_FLOATS 11136  // 44544 B

// ---- ws float offsets ----
#define WS_CS   2048    // c0/c1 (128 f)
#define WS_W2F  2304    // Wd2 K32 A-frags f16 (8192 f = 32KB): [(jt32*8+nt)*64+l]
#define WS_W1F  10496   // Wd1 K32 A-frags f16 (8192 f): [((half*2+ks)*8+jt)*64+l]
#define WS_WMF  18688   // Wm B-frags f16 (2048 f = 8KB)

__global__ void frap_setup(const float* __restrict__ Ws0, const float* __restrict__ bs,
                           const float* __restrict__ Wm,  const float* __restrict__ bm,
                           const float* __restrict__ rel, const float* __restrict__ Wr1,
                           const float* __restrict__ br1, const float* __restrict__ Wr2,
                           const float* __restrict__ br2, const float* __restrict__ Wc,
                           const float* __restrict__ Wd1, const float* __restrict__ Wd2,
                           float* __restrict__ wsf)
{
    __shared__ float hr1[128];
    const int t = threadIdx.x;  // 128 threads
    if (blockIdx.x == 16) {
        const int s = t >> 6, e = t & 63;
        float acc = bm[e];
        for (int h = 0; h < 64; ++h) {
            float hs = fmaxf((s ? Ws0[h] : 0.0f) + bs[h], 0.0f);
            acc = fmaf(hs, Wm[(64 + h) * 64 + e], acc);
        }
        wsf[WS_CS + s * 64 + e] = acc;
    } else if (blockIdx.x == 17) {
        // W2F: K32 A-frags of Wd2 (row n, k j)
        for (int idx = t; idx < 2048; idx += 128) {
            const int l = idx & 63, f = idx >> 6;
            const int jt32 = f >> 3, nt = f & 7;
            half8 v;
#pragma unroll
            for (int kk = 0; kk < 8; ++kk)
                v[kk] = (_Float16)Wd2[(jt32 * 32 + (l >> 4) * 8 + kk) * 128 + nt * 16 + (l & 15)];
            *(half8*)((char*)wsf + WS_W2F * 4 + idx * 16) = v;
        }
    } else if (blockIdx.x == 18) {
        // W1F: K32 A-frags of Wd1 halves (row j, k e)
        for (int idx = t; idx < 2048; idx += 128) {
            const int l = idx & 63, f = idx >> 6;
            const int half = f >> 4, ks = (f >> 3) & 1, jt = f & 7;
            half8 v;
#pragma unroll
            for (int kk = 0; kk < 8; ++kk)
                v[kk] = (_Float16)Wd1[(half * 64 + ks * 32 + (l >> 4) * 8 + kk) * 128 + jt * 16 + (l & 15)];
            *(half8*)((char*)wsf + WS_W1F * 4 + idx * 16) = v;
        }
    } else if (blockIdx.x == 19) {
        // Wm_top[64k][64col] B-frags: f = (tile*2+ks)*64 + lane
        for (int f = t; f < 512; f += 128) {
            const int l = f & 63, ks = (f >> 6) & 1, tile = f >> 7;
            const int kbase = (ks * 4 + (l >> 4)) * 8, col = tile * 16 + (l & 15);
            half8 v;
#pragma unroll
            for (int kk = 0; kk < 8; ++kk)
                v[kk] = (_Float16)Wm[(kbase + kk) * 64 + col];
            *(half8*)((char*)wsf + WS_WMF * 4 + f * 16) = v;
        }
    } else {
        const int pair = blockIdx.x;  // p*4+q
        float a = br1[t];
        for (int r = 0; r < 32; ++r) a = fmaf(rel[pair * 32 + r], Wr1[r * 128 + t], a);
        hr1[t] = fmaxf(a, 0.0f);
        __syncthreads();
        float a2 = br2[t];
        for (int j = 0; j < 128; ++j) a2 = fmaf(hr1[j], Wr2[j * 128 + t], a2);
        wsf[pair * 128 + t] = fmaxf(a2, 0.0f) * Wc[t];  // wc_eff
    }
}

__global__ __launch_bounds__(NT, 6)
void frap_main(const float* __restrict__ mc_g, const float* __restrict__ oh_g,
               const float* __restrict__ Wv_g, const float* __restrict__ bv_g,
               const float* __restrict__ bd1_g, const float* __restrict__ bd2_g,
               const float* __restrict__ bc_g,
               const float* __restrict__ wsf, float* __restrict__ out)
{
    extern __shared__ float lds[];
    const int t = threadIdx.x;
    const int wv = t >> 6, ln = t & 63;
    const int bid = blockIdx.x;

    // ---- consts ----
    if (t < 128) lds[S_BD1 + t] = bd1_g[t];
    else if (t < 256) lds[S_BD2 + (t - 128)] = bd2_g[t - 128];
    else if (t < 384) lds[S_C0 + (t - 256)] = wsf[WS_CS + (t - 256)];
    const float bcv = bc_g[0];

    // ---- Ah[s][r=b*8+mv][64h] = relu(mc*Wv+bv) f16 swz (overlays UV region) ----
    {
        const int r = t >> 3, h8 = (t & 7) * 8;
        float4 wa = *(const float4*)&Wv_g[h8];
        float4 wb = *(const float4*)&Wv_g[h8 + 4];
        float4 ba = *(const float4*)&bv_g[h8];
        float4 bb = *(const float4*)&bv_g[h8 + 4];
#pragma unroll
        for (int s = 0; s < 2; ++s) {
            const float mcv = mc_g[bid * 128 + s * 64 + r];
            half8 v;
            v[0] = (_Float16)fmaxf(fmaf(mcv, wa.x, ba.x), 0.f);
            v[1] = (_Float16)fmaxf(fmaf(mcv, wa.y, ba.y), 0.f);
            v[2] = (_Float16)fmaxf(fmaf(mcv, wa.z, ba.z), 0.f);
            v[3] = (_Float16)fmaxf(fmaf(mcv, wa.w, ba.w), 0.f);
            v[4] = (_Float16)fmaxf(fmaf(mcv, wb.x, bb.x), 0.f);
            v[5] = (_Float16)fmaxf(fmaf(mcv, wb.y, bb.y), 0.f);
            v[6] = (_Float16)fmaxf(fmaf(mcv, wb.z, bb.z), 0.f);
            v[7] = (_Float16)fmaxf(fmaf(mcv, wb.w, bb.w), 0.f);
            *(half8*)((char*)lds + L_AH * 4 + s * 8192 + r * 128
                      + (((t & 7) ^ (r & 7)) << 4)) = v;
        }
    }
    __syncthreads();

    const int lr = ln & 15, lq = ln >> 4;

    // ---- phase-1 MFMA: d_p -> dpH, both tiles share WmF frags ----
    {
        const int rt1 = wv & 3, ch = wv >> 2;
        half8 bf[2][2];
#pragma unroll
        for (int ks = 0; ks < 2; ++ks)
#pragma unroll
            for (int cti = 0; cti < 2; ++cti)
                bf[ks][cti] = *(const half8*)((const char*)wsf + WS_WMF * 4
                              + (((ch * 2 + cti) * 2 + ks) * 64 + ln) * 16);
        f32x4 acc[2][2];
#pragma unroll
        for (int s = 0; s < 2; ++s)
#pragma unroll
            for (int cti = 0; cti < 2; ++cti)
                acc[s][cti] = (f32x4){0.f, 0.f, 0.f, 0.f};
#pragma unroll
        for (int s = 0; s < 2; ++s) {
#pragma unroll
            for (int ks = 0; ks < 2; ++ks) {
                const int c8 = ks * 4 + lq;
                const int r = rt1 * 16 + lr;
                half8 af = *(half8*)((char*)lds + L_AH * 4 + s * 8192 + r * 128
                                     + ((c8 ^ (r & 7)) << 4));
#pragma unroll
                for (int cti = 0; cti < 2; ++cti)
                    acc[s][cti] = __builtin_amdgcn_mfma_f32_16x16x32_f16(af, bf[ks][cti], acc[s][cti], 0, 0, 0);
            }
        }
        const int bloc = rt1 * 2 + (lq >> 1);
#pragma unroll
        for (int s = 0; s < 2; ++s) {
#pragma unroll
            for (int pp = 0; pp < 2; ++pp) {
                const int p = (lq & 1) * 2 + pp;
                const float sv = oh_g[(bid * 16 + s * 8 + bloc) * 4 + p];
                const int csb = (sv > 0.5f) ? S_C1 : S_C0;
                const int row32 = p * 8 + bloc, sw = row32 & 7;
#pragma unroll
                for (int cti = 0; cti < 2; ++cti) {
                    const int e = (ch * 2 + cti) * 16 + lr;
                    const float cs = lds[csb + e];
                    float d0 = fmaxf(acc[s][cti][2 * pp] + cs, 0.f);
                    float d1 = fmaxf(acc[s][cti][2 * pp + 1] + cs, 0.f);
                    *(_Float16*)((char*)lds + L_DPH * 4 + s * 4096 + row32 * 128
                                 + (((e >> 3) ^ sw) << 4) + (e & 7) * 2) = (_Float16)(d0 + d1);
                }
            }
        }
    }
    __syncthreads();   // dpH visible; Ah reads done (UV overwrites Ah region next)

    // ---- UV-GEMM: both tiles share W1F frags ----
    {
        const int half = wv & 1, ct = (wv >> 1) & 1, jh = wv >> 2;
        const int row32 = ct * 16 + lr;
        f32x4 uvacc[2][4];
#pragma unroll
        for (int s = 0; s < 2; ++s)
#pragma unroll
            for (int j4 = 0; j4 < 4; ++j4) {
                if (half == 0)
                    uvacc[s][j4] = *(f32x4*)&lds[S_BD1 + (jh * 4 + j4) * 16 + lq * 4];
                else
                    uvacc[s][j4] = (f32x4){0.f, 0.f, 0.f, 0.f};
            }
#pragma unroll
        for (int ks = 0; ks < 2; ++ks) {
            half8 bfr[2];
#pragma unroll
            for (int s = 0; s < 2; ++s)
                bfr[s] = *(half8*)((char*)lds + L_DPH * 4 + s * 4096 + row32 * 128
                                   + (((ks * 4 + lq) ^ (lr & 7)) << 4));
#pragma unroll
            for (int j4 = 0; j4 < 4; ++j4) {
                half8 afr = *(const half8*)((const char*)wsf + WS_W1F * 4
                            + (((half * 2 + ks) * 8 + jh * 4 + j4) * 64 + ln) * 16);
#pragma unroll
                for (int s = 0; s < 2; ++s)
                    uvacc[s][j4] = __builtin_amdgcn_mfma_f32_16x16x32_f16(afr, bfr[s], uvacc[s][j4], 0, 0, 0);
            }
        }
        const int csw = row32 & 7;
#pragma unroll
        for (int s = 0; s < 2; ++s) {
            char* base = (char*)lds + L_UV * 4 + s * 16384 + half * 8192
                         + row32 * 256 + (lq & 1) * 8;
#pragma unroll
            for (int j4 = 0; j4 < 4; ++j4) {
                const int jt = jh * 4 + j4;
                f32x4 v = uvacc[s][j4];
                half4 hv;
                hv[0] = (_Float16)v[0]; hv[1] = (_Float16)v[1];
                hv[2] = (_Float16)v[2]; hv[3] = (_Float16)v[3];
                *(half4*)(base + (((jt * 2 + (lq >> 1)) ^ csw) << 4)) = hv;
            }
        }
    }
    __syncthreads();   // U/V visible

    // ---- GEMM-2: wave = (rt pair) x (n-half); both tiles share W2F frags ----
    const int rth = wv & 3, nh = wv >> 2;
    const int rt0 = rth * 2;
    const int ucol = rth * 8 + (lr & 7);
    const int vcol0 = lr;
    const int vcol1 = 16 + lr;

    f32x4 acc2[2][2][4];
#pragma unroll
    for (int ntl = 0; ntl < 4; ++ntl) {
        f32x4 b2 = *(f32x4*)&lds[S_BD2 + (nh * 4 + ntl) * 16 + lq * 4];
        acc2[0][0][ntl] = b2; acc2[0][1][ntl] = b2;
        acc2[1][0][ntl] = b2; acc2[1][1][ntl] = b2;
    }

#pragma unroll
    for (int jt32 = 0; jt32 < 4; ++jt32) {
        const int ch = jt32 * 4 + lq;
        half8 w2[4];
#pragma unroll
        for (int ntl = 0; ntl < 4; ++ntl)
            w2[ntl] = *(const half8*)((const char*)wsf + WS_W2F * 4
                                      + ((jt32 * 8 + nh * 4 + ntl) * 64 + ln) * 16);
#pragma unroll
        for (int s = 0; s < 2; ++s) {
            char* uvb = (char*)lds + L_UV * 4 + s * 16384;
            half8 u  = *(half8*)(uvb + ucol * 256 + ((ch ^ (ucol & 7)) << 4));
            half8 v0 = *(half8*)(uvb + 8192 + vcol0 * 256 + ((ch ^ (vcol0 & 7)) << 4));
            half8 v1 = *(half8*)(uvb + 8192 + vcol1 * 256 + ((ch ^ (vcol1 & 7)) << 4));
            half8 s0 = u + v0;
            half8 s1 = u + v1;
#if __has_builtin(__builtin_elementwise_max)
            half8 z = {};
            s0 = __builtin_elementwise_max(s0, z);
            s1 = __builtin_elementwise_max(s1, z);
#else
            us8 b0 = __builtin_bit_cast(us8, s0);
            us8 m0 = (b0 >> 15) - (us8)1; b0 &= m0;
            s0 = __builtin_bit_cast(half8, b0);
            us8 b1 = __builtin_bit_cast(us8, s1);
            us8 m1 = (b1 >> 15) - (us8)1; b1 &= m1;
            s1 = __builtin_bit_cast(half8, b1);
#endif
#pragma unroll
            for (int ntl = 0; ntl < 4; ++ntl) {
                acc2[s][0][ntl] = __builtin_amdgcn_mfma_f32_16x16x32_f16(w2[ntl], s0, acc2[s][0][ntl], 0, 0, 0);
                acc2[s][1][ntl] = __builtin_amdgcn_mfma_f32_16x16x32_f16(w2[ntl], s1, acc2[s][1][ntl], 0, 0, 0);
            }
        }
    }

    // ---- epilogue: relu * wc_eff (wc shared across s), shfl, partials to LDS ----
#pragma unroll
    for (int i = 0; i < 2; ++i) {
        const int pair = (rt0 + i) * 2 + (lr >> 3);
        const float* wcr = &wsf[pair * 128 + lq * 4];
        f32x4 wc[4];
#pragma unroll
        for (int ntl = 0; ntl < 4; ++ntl)
            wc[ntl] = *(const f32x4*)&wcr[(nh * 4 + ntl) * 16];
#pragma unroll
        for (int s = 0; s < 2; ++s) {
            float tot = 0.f;
#pragma unroll
            for (int ntl = 0; ntl < 4; ++ntl)
#pragma unroll
                for (int r2 = 0; r2 < 4; ++r2)
                    tot = fmaf(fmaxf(acc2[s][i][ntl][r2], 0.f), wc[ntl][r2], tot);
            tot += __shfl_xor(tot, 16, 64);
            tot += __shfl_xor(tot, 32, 64);
            if (lq == 0)
                lds[S_SP + s * 256 + nh * 128 + (rt0 + i) * 16 + lr] = tot;
        }
    }
    __syncthreads();

    if (t < 64) {
        const int s = t >> 5, tt = t & 31;
        const int r0 = tt * 4;
        float o = 0.f;
#pragma unroll
        for (int d = 0; d < 4; ++d) {
            const int r = r0 + d;
            o += fmaxf(lds[S_SP + s * 256 + r] + lds[S_SP + s * 256 + 128 + r] + bcv, 0.f);
        }
        out[(r0 >> 5) * 32768 + ((r0 >> 3) & 3) * 8192 + (bid * 2 + s) * 2 + ((r0 & 7) >> 2)] = o;
    }
}

extern "C" void kernel_launch(void* const* d_in, const int* in_sizes, int n_in,
                              void* d_out, int out_size, void* d_ws, size_t ws_size,
                              hipStream_t stream) {
    (void)in_sizes; (void)n_in; (void)out_size; (void)ws_size;
    const float* mc  = (const float*)d_in[0];
    const float* oh  = (const float*)d_in[1];
    const float* Wv  = (const float*)d_in[2];
    const float* bv  = (const float*)d_in[3];
    const float* Ws  = (const float*)d_in[4];
    const float* bs  = (const float*)d_in[5];
    const float* Wm  = (const float*)d_in[6];
    const float* bm  = (const float*)d_in[7];
    const float* rel = (const float*)d_in[8];
    const float* Wd1 = (const float*)d_in[9];
    const float* bd1 = (const float*)d_in[10];
    const float* Wd2 = (const float*)d_in[11];
    const float* bd2 = (const float*)d_in[12];
    const float* Wr1 = (const float*)d_in[13];
    const float* br1 = (const float*)d_in[14];
    const float* Wr2 = (const float*)d_in[15];
    const float* br2 = (const float*)d_in[16];
    const float* Wc  = (const float*)d_in[17];
    const float* bc  = (const float*)d_in[18];
    float* wsf = (float*)d_ws;
    float* out = (float*)d_out;

    hipLaunchKernelGGL(frap_setup, dim3(20), dim3(128), 0, stream,
                       Ws, bs, Wm, bm, rel, Wr1, br1, Wr2, br2, Wc, Wd1, Wd2, wsf);
    hipLaunchKernelGGL(frap_main, dim3(NBLK), dim3(NT), LDS_FLOATS * 4, stream,
                       mc, oh, Wv, bv, bd1, bd2, bc, wsf, out);
}

// Round 13
// 54.012 us; speedup vs baseline: 3.5969x; 3.5969x over previous
//
#include <hip/hip_runtime.h>

#define NT   512
#define NBLK 2048   // B/16 : 2 batch-tiles of 64 per block

typedef _Float16 half8 __attribute__((ext_vector_type(8)));
typedef _Float16 half4 __attribute__((ext_vector_type(4)));
typedef unsigned short us8 __attribute__((ext_vector_type(8)));
typedef float    f32x4 __attribute__((ext_vector_type(4)));

// ---- LDS float offsets (60.9 KB -> 2 blocks/CU) ----
#define L_AH   0          // [2][64][32] f : Ah f16 swz, 8KB/tile
#define L_DPH  4096       // [2][32][32] f : dpH f16 swz, 4KB/tile
#define L_UV   6144       // [2][2 half][32 col][64] f : U/V f16 swz, 16KB/tile
#define S_BD1  14336      // 128
#define S_BD2  14464      // 128
#define S_C0   14592      // 64
#define S_C1   14656      // 64
#define S_SP   14720      // [2][2][128] partial sums
#define LDS_FLOATS 15232  // 60928 B

// ---- ws float offsets ----
#define WS_CS   2048    // c0/c1 (128 f)
#define WS_W2F  2304    // Wd2 K32 A-frags f16 (8192 f = 32KB): [(jt32*8+nt)*64+l]
#define WS_W1F  10496   // Wd1 K32 A-frags f16 (8192 f): [((half*2+ks)*8+jt)*64+l]
#define WS_WMF  18688   // Wm B-frags f16 (2048 f = 8KB)

__global__ void frap_setup(const float* __restrict__ Ws0, const float* __restrict__ bs,
                           const float* __restrict__ Wm,  const float* __restrict__ bm,
                           const float* __restrict__ rel, const float* __restrict__ Wr1,
                           const float* __restrict__ br1, const float* __restrict__ Wr2,
                           const float* __restrict__ br2, const float* __restrict__ Wc,
                           const float* __restrict__ Wd1, const float* __restrict__ Wd2,
                           float* __restrict__ wsf)
{
    __shared__ float hr1[128];
    const int t = threadIdx.x;  // 128 threads
    if (blockIdx.x == 16) {
        const int s = t >> 6, e = t & 63;
        float acc = bm[e];
        for (int h = 0; h < 64; ++h) {
            float hs = fmaxf((s ? Ws0[h] : 0.0f) + bs[h], 0.0f);
            acc = fmaf(hs, Wm[(64 + h) * 64 + e], acc);
        }
        wsf[WS_CS + s * 64 + e] = acc;
    } else if (blockIdx.x == 17) {
        // W2F: K32 A-frags of Wd2 (row n, k j)
        for (int idx = t; idx < 2048; idx += 128) {
            const int l = idx & 63, f = idx >> 6;
            const int jt32 = f >> 3, nt = f & 7;
            half8 v;
#pragma unroll
            for (int kk = 0; kk < 8; ++kk)
                v[kk] = (_Float16)Wd2[(jt32 * 32 + (l >> 4) * 8 + kk) * 128 + nt * 16 + (l & 15)];
            *(half8*)((char*)wsf + WS_W2F * 4 + idx * 16) = v;
        }
    } else if (blockIdx.x == 18) {
        // W1F: K32 A-frags of Wd1 halves (row j, k e)
        for (int idx = t; idx < 2048; idx += 128) {
            const int l = idx & 63, f = idx >> 6;
            const int half = f >> 4, ks = (f >> 3) & 1, jt = f & 7;
            half8 v;
#pragma unroll
            for (int kk = 0; kk < 8; ++kk)
                v[kk] = (_Float16)Wd1[(half * 64 + ks * 32 + (l >> 4) * 8 + kk) * 128 + jt * 16 + (l & 15)];
            *(half8*)((char*)wsf + WS_W1F * 4 + idx * 16) = v;
        }
    } else if (blockIdx.x == 19) {
        // Wm_top[64k][64col] B-frags: f = (tile*2+ks)*64 + lane
        for (int f = t; f < 512; f += 128) {
            const int l = f & 63, ks = (f >> 6) & 1, tile = f >> 7;
            const int kbase = (ks * 4 + (l >> 4)) * 8, col = tile * 16 + (l & 15);
            half8 v;
#pragma unroll
            for (int kk = 0; kk < 8; ++kk)
                v[kk] = (_Float16)Wm[(kbase + kk) * 64 + col];
            *(half8*)((char*)wsf + WS_WMF * 4 + f * 16) = v;
        }
    } else {
        const int pair = blockIdx.x;  // p*4+q
        float a = br1[t];
        for (int r = 0; r < 32; ++r) a = fmaf(rel[pair * 32 + r], Wr1[r * 128 + t], a);
        hr1[t] = fmaxf(a, 0.0f);
        __syncthreads();
        float a2 = br2[t];
        for (int j = 0; j < 128; ++j) a2 = fmaf(hr1[j], Wr2[j * 128 + t], a2);
        wsf[pair * 128 + t] = fmaxf(a2, 0.0f) * Wc[t];  // wc_eff
    }
}

__global__ __launch_bounds__(NT, 2)
void frap_main(const float* __restrict__ mc_g, const float* __restrict__ oh_g,
               const float* __restrict__ Wv_g, const float* __restrict__ bv_g,
               const float* __restrict__ bd1_g, const float* __restrict__ bd2_g,
               const float* __restrict__ bc_g,
               const float* __restrict__ wsf, float* __restrict__ out)
{
    extern __shared__ float lds[];
    const int t = threadIdx.x;
    const int wv = t >> 6, ln = t & 63;
    const int bid = blockIdx.x;

    // ---- consts ----
    if (t < 128) lds[S_BD1 + t] = bd1_g[t];
    else if (t < 256) lds[S_BD2 + (t - 128)] = bd2_g[t - 128];
    else if (t < 384) lds[S_C0 + (t - 256)] = wsf[WS_CS + (t - 256)];
    const float bcv = bc_g[0];

    // ---- Ah[s][r=b*8+mv][64h] = relu(mc*Wv+bv) f16 swz ----
    {
        const int r = t >> 3, h8 = (t & 7) * 8;
        float4 wa = *(const float4*)&Wv_g[h8];
        float4 wb = *(const float4*)&Wv_g[h8 + 4];
        float4 ba = *(const float4*)&bv_g[h8];
        float4 bb = *(const float4*)&bv_g[h8 + 4];
#pragma unroll
        for (int s = 0; s < 2; ++s) {
            const float mcv = mc_g[bid * 128 + s * 64 + r];
            half8 v;
            v[0] = (_Float16)fmaxf(fmaf(mcv, wa.x, ba.x), 0.f);
            v[1] = (_Float16)fmaxf(fmaf(mcv, wa.y, ba.y), 0.f);
            v[2] = (_Float16)fmaxf(fmaf(mcv, wa.z, ba.z), 0.f);
            v[3] = (_Float16)fmaxf(fmaf(mcv, wa.w, ba.w), 0.f);
            v[4] = (_Float16)fmaxf(fmaf(mcv, wb.x, bb.x), 0.f);
            v[5] = (_Float16)fmaxf(fmaf(mcv, wb.y, bb.y), 0.f);
            v[6] = (_Float16)fmaxf(fmaf(mcv, wb.z, bb.z), 0.f);
            v[7] = (_Float16)fmaxf(fmaf(mcv, wb.w, bb.w), 0.f);
            *(half8*)((char*)lds + L_AH * 4 + s * 8192 + r * 128
                      + (((t & 7) ^ (r & 7)) << 4)) = v;
        }
    }
    __syncthreads();

    const int lr = ln & 15, lq = ln >> 4;

    // ---- phase-1 MFMA: d_p -> dpH, both tiles share WmF frags ----
    {
        const int rt1 = wv & 3, ch = wv >> 2;
        const int bloc = rt1 * 2 + (lq >> 1);
        // hoist oh loads: latency hides under the MFMA cluster below
        float sv[2][2];
#pragma unroll
        for (int s = 0; s < 2; ++s)
#pragma unroll
            for (int pp = 0; pp < 2; ++pp)
                sv[s][pp] = oh_g[(bid * 16 + s * 8 + bloc) * 4 + (lq & 1) * 2 + pp];

        half8 bf[2][2];
#pragma unroll
        for (int ks = 0; ks < 2; ++ks)
#pragma unroll
            for (int cti = 0; cti < 2; ++cti)
                bf[ks][cti] = *(const half8*)((const char*)wsf + WS_WMF * 4
                              + (((ch * 2 + cti) * 2 + ks) * 64 + ln) * 16);
        f32x4 acc[2][2];
#pragma unroll
        for (int s = 0; s < 2; ++s)
#pragma unroll
            for (int cti = 0; cti < 2; ++cti)
                acc[s][cti] = (f32x4){0.f, 0.f, 0.f, 0.f};
        __builtin_amdgcn_s_setprio(1);
#pragma unroll
        for (int s = 0; s < 2; ++s) {
#pragma unroll
            for (int ks = 0; ks < 2; ++ks) {
                const int c8 = ks * 4 + lq;
                const int r = rt1 * 16 + lr;
                half8 af = *(half8*)((char*)lds + L_AH * 4 + s * 8192 + r * 128
                                     + ((c8 ^ (r & 7)) << 4));
#pragma unroll
                for (int cti = 0; cti < 2; ++cti)
                    acc[s][cti] = __builtin_amdgcn_mfma_f32_16x16x32_f16(af, bf[ks][cti], acc[s][cti], 0, 0, 0);
            }
        }
        __builtin_amdgcn_s_setprio(0);
#pragma unroll
        for (int s = 0; s < 2; ++s) {
#pragma unroll
            for (int pp = 0; pp < 2; ++pp) {
                const int p = (lq & 1) * 2 + pp;
                const int csb = (sv[s][pp] > 0.5f) ? S_C1 : S_C0;
                const int row32 = p * 8 + bloc, sw = row32 & 7;
#pragma unroll
                for (int cti = 0; cti < 2; ++cti) {
                    const int e = (ch * 2 + cti) * 16 + lr;
                    const float cs = lds[csb + e];
                    float d0 = fmaxf(acc[s][cti][2 * pp] + cs, 0.f);
                    float d1 = fmaxf(acc[s][cti][2 * pp + 1] + cs, 0.f);
                    *(_Float16*)((char*)lds + L_DPH * 4 + s * 4096 + row32 * 128
                                 + (((e >> 3) ^ sw) << 4) + (e & 7) * 2) = (_Float16)(d0 + d1);
                }
            }
        }
    }
    __syncthreads();   // dpH visible

    // ---- UV-GEMM: both tiles share W1F frags ----
    {
        const int half = wv & 1, ct = (wv >> 1) & 1, jh = wv >> 2;
        const int row32 = ct * 16 + lr;
        f32x4 uvacc[2][4];
#pragma unroll
        for (int s = 0; s < 2; ++s)
#pragma unroll
            for (int j4 = 0; j4 < 4; ++j4) {
                if (half == 0)
                    uvacc[s][j4] = *(f32x4*)&lds[S_BD1 + (jh * 4 + j4) * 16 + lq * 4];
                else
                    uvacc[s][j4] = (f32x4){0.f, 0.f, 0.f, 0.f};
            }
        __builtin_amdgcn_s_setprio(1);
#pragma unroll
        for (int ks = 0; ks < 2; ++ks) {
            half8 bfr[2];
#pragma unroll
            for (int s = 0; s < 2; ++s)
                bfr[s] = *(half8*)((char*)lds + L_DPH * 4 + s * 4096 + row32 * 128
                                   + (((ks * 4 + lq) ^ (lr & 7)) << 4));
#pragma unroll
            for (int j4 = 0; j4 < 4; ++j4) {
                half8 afr = *(const half8*)((const char*)wsf + WS_W1F * 4
                            + (((half * 2 + ks) * 8 + jh * 4 + j4) * 64 + ln) * 16);
#pragma unroll
                for (int s = 0; s < 2; ++s)
                    uvacc[s][j4] = __builtin_amdgcn_mfma_f32_16x16x32_f16(afr, bfr[s], uvacc[s][j4], 0, 0, 0);
            }
        }
        __builtin_amdgcn_s_setprio(0);
        const int csw = row32 & 7;
#pragma unroll
        for (int s = 0; s < 2; ++s) {
            char* base = (char*)lds + L_UV * 4 + s * 16384 + half * 8192
                         + row32 * 256 + (lq & 1) * 8;
#pragma unroll
            for (int j4 = 0; j4 < 4; ++j4) {
                const int jt = jh * 4 + j4;
                f32x4 v = uvacc[s][j4];
                half4 hv;
                hv[0] = (_Float16)v[0]; hv[1] = (_Float16)v[1];
                hv[2] = (_Float16)v[2]; hv[3] = (_Float16)v[3];
                *(half4*)(base + (((jt * 2 + (lq >> 1)) ^ csw) << 4)) = hv;
            }
        }
    }
    __syncthreads();   // U/V visible

    // ---- GEMM-2: wave = (rt pair) x (n-half); both tiles share W2F frags ----
    const int rth = wv & 3, nh = wv >> 2;
    const int rt0 = rth * 2;
    const int ucol = rth * 8 + (lr & 7);
    const int vcol0 = lr;
    const int vcol1 = 16 + lr;

    f32x4 acc2[2][2][4];
#pragma unroll
    for (int ntl = 0; ntl < 4; ++ntl) {
        f32x4 b2 = *(f32x4*)&lds[S_BD2 + (nh * 4 + ntl) * 16 + lq * 4];
        acc2[0][0][ntl] = b2; acc2[0][1][ntl] = b2;
        acc2[1][0][ntl] = b2; acc2[1][1][ntl] = b2;
    }

#pragma unroll
    for (int jt32 = 0; jt32 < 4; ++jt32) {
        const int ch = jt32 * 4 + lq;
        half8 w2[4];
#pragma unroll
        for (int ntl = 0; ntl < 4; ++ntl)
            w2[ntl] = *(const half8*)((const char*)wsf + WS_W2F * 4
                                      + ((jt32 * 8 + nh * 4 + ntl) * 64 + ln) * 16);
#pragma unroll
        for (int s = 0; s < 2; ++s) {
            char* uvb = (char*)lds + L_UV * 4 + s * 16384;
            half8 u  = *(half8*)(uvb + ucol * 256 + ((ch ^ (ucol & 7)) << 4));
            half8 v0 = *(half8*)(uvb + 8192 + vcol0 * 256 + ((ch ^ (vcol0 & 7)) << 4));
            half8 v1 = *(half8*)(uvb + 8192 + vcol1 * 256 + ((ch ^ (vcol1 & 7)) << 4));
            half8 s0 = u + v0;
            half8 s1 = u + v1;
#if __has_builtin(__builtin_elementwise_max)
            half8 z = {};
            s0 = __builtin_elementwise_max(s0, z);
            s1 = __builtin_elementwise_max(s1, z);
#else
            us8 b0 = __builtin_bit_cast(us8, s0);
            us8 m0 = (b0 >> 15) - (us8)1; b0 &= m0;
            s0 = __builtin_bit_cast(half8, b0);
            us8 b1 = __builtin_bit_cast(us8, s1);
            us8 m1 = (b1 >> 15) - (us8)1; b1 &= m1;
            s1 = __builtin_bit_cast(half8, b1);
#endif
            __builtin_amdgcn_s_setprio(1);
#pragma unroll
            for (int ntl = 0; ntl < 4; ++ntl) {
                acc2[s][0][ntl] = __builtin_amdgcn_mfma_f32_16x16x32_f16(w2[ntl], s0, acc2[s][0][ntl], 0, 0, 0);
                acc2[s][1][ntl] = __builtin_amdgcn_mfma_f32_16x16x32_f16(w2[ntl], s1, acc2[s][1][ntl], 0, 0, 0);
            }
            __builtin_amdgcn_s_setprio(0);
        }
    }

    // ---- epilogue: relu * wc_eff (wc shared across s), shfl, partials to LDS ----
#pragma unroll
    for (int i = 0; i < 2; ++i) {
        const int pair = (rt0 + i) * 2 + (lr >> 3);
        const float* wcr = &wsf[pair * 128 + lq * 4];
        f32x4 wc[4];
#pragma unroll
        for (int ntl = 0; ntl < 4; ++ntl)
            wc[ntl] = *(const f32x4*)&wcr[(nh * 4 + ntl) * 16];
#pragma unroll
        for (int s = 0; s < 2; ++s) {
            float tot = 0.f;
#pragma unroll
            for (int ntl = 0; ntl < 4; ++ntl)
#pragma unroll
                for (int r2 = 0; r2 < 4; ++r2)
                    tot = fmaf(fmaxf(acc2[s][i][ntl][r2], 0.f), wc[ntl][r2], tot);
            tot += __shfl_xor(tot, 16, 64);
            tot += __shfl_xor(tot, 32, 64);
            if (lq == 0)
                lds[S_SP + s * 256 + nh * 128 + (rt0 + i) * 16 + lr] = tot;
        }
    }
    __syncthreads();

    if (t < 64) {
        const int s = t >> 5, tt = t & 31;
        const int r0 = tt * 4;
        float o = 0.f;
#pragma unroll
        for (int d = 0; d < 4; ++d) {
            const int r = r0 + d;
            o += fmaxf(lds[S_SP + s * 256 + r] + lds[S_SP + s * 256 + 128 + r] + bcv, 0.f);
        }
        out[(r0 >> 5) * 32768 + ((r0 >> 3) & 3) * 8192 + (bid * 2 + s) * 2 + ((r0 & 7) >> 2)] = o;
    }
}

extern "C" void kernel_launch(void* const* d_in, const int* in_sizes, int n_in,
                              void* d_out, int out_size, void* d_ws, size_t ws_size,
                              hipStream_t stream) {
    (void)in_sizes; (void)n_in; (void)out_size; (void)ws_size;
    const float* mc  = (const float*)d_in[0];
    const float* oh  = (const float*)d_in[1];
    const float* Wv  = (const float*)d_in[2];
    const float* bv  = (const float*)d_in[3];
    const float* Ws  = (const float*)d_in[4];
    const float* bs  = (const float*)d_in[5];
    const float* Wm  = (const float*)d_in[6];
    const float* bm  = (const float*)d_in[7];
    const float* rel = (const float*)d_in[8];
    const float* Wd1 = (const float*)d_in[9];
    const float* bd1 = (const float*)d_in[10];
    const float* Wd2 = (const float*)d_in[11];
    const float* bd2 = (const float*)d_in[12];
    const float* Wr1 = (const float*)d_in[13];
    const float* br1 = (const float*)d_in[14];
    const float* Wr2 = (const float*)d_in[15];
    const float* br2 = (const float*)d_in[16];
    const float* Wc  = (const float*)d_in[17];
    const float* bc  = (const float*)d_in[18];
    float* wsf = (float*)d_ws;
    float* out = (float*)d_out;

    hipLaunchKernelGGL(frap_setup, dim3(20), dim3(128), 0, stream,
                       Ws, bs, Wm, bm, rel, Wr1, br1, Wr2, br2, Wc, Wd1, Wd2, wsf);
    hipLaunchKernelGGL(frap_main, dim3(NBLK), dim3(NT), LDS_FLOATS * 4, stream,
                       mc, oh, Wv, bv, bd1, bd2, bc, wsf, out);
}

// Round 14
// 43.889 us; speedup vs baseline: 4.4265x; 1.2306x over previous
//
#include <hip/hip_runtime.h>

#define NT   512
#define NBLK 2048   // B/16 : 2 batch-tiles of 64 per block

typedef _Float16 half8 __attribute__((ext_vector_type(8)));
typedef _Float16 half4 __attribute__((ext_vector_type(4)));
typedef unsigned short us8 __attribute__((ext_vector_type(8)));
typedef float    f32x4 __attribute__((ext_vector_type(4)));

// ---- LDS float offsets (60.9 KB -> 2 blocks/CU) ----
#define L_AH   0          // [2][64][32] f : Ah f16 swz, 8KB/tile
#define L_DPH  4096       // [2][32][32] f : dpH f16 swz, 4KB/tile
#define L_UV   6144       // [2][2 half][32 col][64] f : U/V f16 swz, 16KB/tile
#define S_BD1  14336      // 128
#define S_BD2  14464      // 128
#define S_C0   14592      // 64
#define S_C1   14656      // 64
#define S_SP   14720      // [2][2][128] partial sums
#define LDS_FLOATS 15232  // 60928 B

// ---- ws float offsets ----
#define WS_CS   2048    // c0/c1 (128 f)
#define WS_W2F  2304    // Wd2 K32 A-frags f16 (8192 f = 32KB): [(jt32*8+nt)*64+l]
#define WS_W1F  10496   // Wd1 K32 A-frags f16 (8192 f): [((half*2+ks)*8+jt)*64+l]
#define WS_WMF  18688   // Wm B-frags f16 (2048 f = 8KB)

__global__ void frap_setup(const float* __restrict__ Ws0, const float* __restrict__ bs,
                           const float* __restrict__ Wm,  const float* __restrict__ bm,
                           const float* __restrict__ rel, const float* __restrict__ Wr1,
                           const float* __restrict__ br1, const float* __restrict__ Wr2,
                           const float* __restrict__ br2, const float* __restrict__ Wc,
                           const float* __restrict__ Wd1, const float* __restrict__ Wd2,
                           float* __restrict__ wsf)
{
    __shared__ float hr1[128];
    const int t = threadIdx.x;  // 128 threads
    if (blockIdx.x == 16) {
        const int s = t >> 6, e = t & 63;
        float acc = bm[e];
        for (int h = 0; h < 64; ++h) {
            float hs = fmaxf((s ? Ws0[h] : 0.0f) + bs[h], 0.0f);
            acc = fmaf(hs, Wm[(64 + h) * 64 + e], acc);
        }
        wsf[WS_CS + s * 64 + e] = acc;
    } else if (blockIdx.x == 17) {
        // W2F: K32 A-frags of Wd2 (row n, k j)
        for (int idx = t; idx < 2048; idx += 128) {
            const int l = idx & 63, f = idx >> 6;
            const int jt32 = f >> 3, nt = f & 7;
            half8 v;
#pragma unroll
            for (int kk = 0; kk < 8; ++kk)
                v[kk] = (_Float16)Wd2[(jt32 * 32 + (l >> 4) * 8 + kk) * 128 + nt * 16 + (l & 15)];
            *(half8*)((char*)wsf + WS_W2F * 4 + idx * 16) = v;
        }
    } else if (blockIdx.x == 18) {
        // W1F: K32 A-frags of Wd1 halves (row j, k e)
        for (int idx = t; idx < 2048; idx += 128) {
            const int l = idx & 63, f = idx >> 6;
            const int half = f >> 4, ks = (f >> 3) & 1, jt = f & 7;
            half8 v;
#pragma unroll
            for (int kk = 0; kk < 8; ++kk)
                v[kk] = (_Float16)Wd1[(half * 64 + ks * 32 + (l >> 4) * 8 + kk) * 128 + jt * 16 + (l & 15)];
            *(half8*)((char*)wsf + WS_W1F * 4 + idx * 16) = v;
        }
    } else if (blockIdx.x == 19) {
        // Wm_top[64k][64col] B-frags: f = (tile*2+ks)*64 + lane
        for (int f = t; f < 512; f += 128) {
            const int l = f & 63, ks = (f >> 6) & 1, tile = f >> 7;
            const int kbase = (ks * 4 + (l >> 4)) * 8, col = tile * 16 + (l & 15);
            half8 v;
#pragma unroll
            for (int kk = 0; kk < 8; ++kk)
                v[kk] = (_Float16)Wm[(kbase + kk) * 64 + col];
            *(half8*)((char*)wsf + WS_WMF * 4 + f * 16) = v;
        }
    } else {
        const int pair = blockIdx.x;  // p*4+q
        float a = br1[t];
        for (int r = 0; r < 32; ++r) a = fmaf(rel[pair * 32 + r], Wr1[r * 128 + t], a);
        hr1[t] = fmaxf(a, 0.0f);
        __syncthreads();
        float a2 = br2[t];
        for (int j = 0; j < 128; ++j) a2 = fmaf(hr1[j], Wr2[j * 128 + t], a2);
        wsf[pair * 128 + t] = fmaxf(a2, 0.0f) * Wc[t];  // wc_eff
    }
}

__global__ __launch_bounds__(NT, 2)
void frap_main(const float* __restrict__ mc_g, const float* __restrict__ oh_g,
               const float* __restrict__ Wv_g, const float* __restrict__ bv_g,
               const float* __restrict__ bd1_g, const float* __restrict__ bd2_g,
               const float* __restrict__ bc_g,
               const float* __restrict__ wsf, float* __restrict__ out)
{
    extern __shared__ float lds[];
    const int t = threadIdx.x;
    const int wv = t >> 6, ln = t & 63;
    const int bid = blockIdx.x;

    // ---- consts ----
    if (t < 128) lds[S_BD1 + t] = bd1_g[t];
    else if (t < 256) lds[S_BD2 + (t - 128)] = bd2_g[t - 128];
    else if (t < 384) lds[S_C0 + (t - 256)] = wsf[WS_CS + (t - 256)];
    const float bcv = bc_g[0];

    // ---- Ah[s][r=b*8+mv][64h] = relu(mc*Wv+bv) f16 swz ----
    {
        const int r = t >> 3, h8 = (t & 7) * 8;
        float4 wa = *(const float4*)&Wv_g[h8];
        float4 wb = *(const float4*)&Wv_g[h8 + 4];
        float4 ba = *(const float4*)&bv_g[h8];
        float4 bb = *(const float4*)&bv_g[h8 + 4];
#pragma unroll
        for (int s = 0; s < 2; ++s) {
            const float mcv = mc_g[bid * 128 + s * 64 + r];
            half8 v;
            v[0] = (_Float16)fmaxf(fmaf(mcv, wa.x, ba.x), 0.f);
            v[1] = (_Float16)fmaxf(fmaf(mcv, wa.y, ba.y), 0.f);
            v[2] = (_Float16)fmaxf(fmaf(mcv, wa.z, ba.z), 0.f);
            v[3] = (_Float16)fmaxf(fmaf(mcv, wa.w, ba.w), 0.f);
            v[4] = (_Float16)fmaxf(fmaf(mcv, wb.x, bb.x), 0.f);
            v[5] = (_Float16)fmaxf(fmaf(mcv, wb.y, bb.y), 0.f);
            v[6] = (_Float16)fmaxf(fmaf(mcv, wb.z, bb.z), 0.f);
            v[7] = (_Float16)fmaxf(fmaf(mcv, wb.w, bb.w), 0.f);
            *(half8*)((char*)lds + L_AH * 4 + s * 8192 + r * 128
                      + (((t & 7) ^ (r & 7)) << 4)) = v;
        }
    }
    __syncthreads();

    const int lr = ln & 15, lq = ln >> 4;

    // ---- phase-1 MFMA: d_p -> dpH, both tiles share WmF frags ----
    {
        const int rt1 = wv & 3, ch = wv >> 2;
        // issue global WmF loads first so L2 latency overlaps the LDS reads
        half8 bf[2][2];
#pragma unroll
        for (int ks = 0; ks < 2; ++ks)
#pragma unroll
            for (int cti = 0; cti < 2; ++cti)
                bf[ks][cti] = *(const half8*)((const char*)wsf + WS_WMF * 4
                              + (((ch * 2 + cti) * 2 + ks) * 64 + ln) * 16);
        f32x4 acc[2][2];
#pragma unroll
        for (int s = 0; s < 2; ++s)
#pragma unroll
            for (int cti = 0; cti < 2; ++cti)
                acc[s][cti] = (f32x4){0.f, 0.f, 0.f, 0.f};
#pragma unroll
        for (int s = 0; s < 2; ++s) {
#pragma unroll
            for (int ks = 0; ks < 2; ++ks) {
                const int c8 = ks * 4 + lq;
                const int r = rt1 * 16 + lr;
                half8 af = *(half8*)((char*)lds + L_AH * 4 + s * 8192 + r * 128
                                     + ((c8 ^ (r & 7)) << 4));
#pragma unroll
                for (int cti = 0; cti < 2; ++cti)
                    acc[s][cti] = __builtin_amdgcn_mfma_f32_16x16x32_f16(af, bf[ks][cti], acc[s][cti], 0, 0, 0);
            }
        }
        const int bloc = rt1 * 2 + (lq >> 1);
#pragma unroll
        for (int s = 0; s < 2; ++s) {
#pragma unroll
            for (int pp = 0; pp < 2; ++pp) {
                const int p = (lq & 1) * 2 + pp;
                const float sv = oh_g[(bid * 16 + s * 8 + bloc) * 4 + p];
                const int csb = (sv > 0.5f) ? S_C1 : S_C0;
                const int row32 = p * 8 + bloc, sw = row32 & 7;
#pragma unroll
                for (int cti = 0; cti < 2; ++cti) {
                    const int e = (ch * 2 + cti) * 16 + lr;
                    const float cs = lds[csb + e];
                    float d0 = fmaxf(acc[s][cti][2 * pp] + cs, 0.f);
                    float d1 = fmaxf(acc[s][cti][2 * pp + 1] + cs, 0.f);
                    *(_Float16*)((char*)lds + L_DPH * 4 + s * 4096 + row32 * 128
                                 + (((e >> 3) ^ sw) << 4) + (e & 7) * 2) = (_Float16)(d0 + d1);
                }
            }
        }
    }
    __syncthreads();   // dpH visible

    // ---- UV-GEMM: both tiles share W1F frags ----
    {
        const int half = wv & 1, ct = (wv >> 1) & 1, jh = wv >> 2;
        const int row32 = ct * 16 + lr;
        f32x4 uvacc[2][4];
#pragma unroll
        for (int s = 0; s < 2; ++s)
#pragma unroll
            for (int j4 = 0; j4 < 4; ++j4) {
                if (half == 0)
                    uvacc[s][j4] = *(f32x4*)&lds[S_BD1 + (jh * 4 + j4) * 16 + lq * 4];
                else
                    uvacc[s][j4] = (f32x4){0.f, 0.f, 0.f, 0.f};
            }
#pragma unroll
        for (int ks = 0; ks < 2; ++ks) {
            half8 bfr[2];
#pragma unroll
            for (int s = 0; s < 2; ++s)
                bfr[s] = *(half8*)((char*)lds + L_DPH * 4 + s * 4096 + row32 * 128
                                   + (((ks * 4 + lq) ^ (lr & 7)) << 4));
#pragma unroll
            for (int j4 = 0; j4 < 4; ++j4) {
                half8 afr = *(const half8*)((const char*)wsf + WS_W1F * 4
                            + (((half * 2 + ks) * 8 + jh * 4 + j4) * 64 + ln) * 16);
#pragma unroll
                for (int s = 0; s < 2; ++s)
                    uvacc[s][j4] = __builtin_amdgcn_mfma_f32_16x16x32_f16(afr, bfr[s], uvacc[s][j4], 0, 0, 0);
            }
        }
        const int csw = row32 & 7;
#pragma unroll
        for (int s = 0; s < 2; ++s) {
            char* base = (char*)lds + L_UV * 4 + s * 16384 + half * 8192
                         + row32 * 256 + (lq & 1) * 8;
#pragma unroll
            for (int j4 = 0; j4 < 4; ++j4) {
                const int jt = jh * 4 + j4;
                f32x4 v = uvacc[s][j4];
                half4 hv;
                hv[0] = (_Float16)v[0]; hv[1] = (_Float16)v[1];
                hv[2] = (_Float16)v[2]; hv[3] = (_Float16)v[3];
                *(half4*)(base + (((jt * 2 + (lq >> 1)) ^ csw) << 4)) = hv;
            }
        }
    }
    __syncthreads();   // U/V visible

    // ---- GEMM-2: wave = (rt pair) x (n-half); both tiles share W2F frags ----
    const int rth = wv & 3, nh = wv >> 2;
    const int rt0 = rth * 2;
    const int ucol = rth * 8 + (lr & 7);
    const int vcol0 = lr;
    const int vcol1 = 16 + lr;

    f32x4 acc2[2][2][4];
#pragma unroll
    for (int ntl = 0; ntl < 4; ++ntl) {
        f32x4 b2 = *(f32x4*)&lds[S_BD2 + (nh * 4 + ntl) * 16 + lq * 4];
        acc2[0][0][ntl] = b2; acc2[0][1][ntl] = b2;
        acc2[1][0][ntl] = b2; acc2[1][1][ntl] = b2;
    }

#pragma unroll
    for (int jt32 = 0; jt32 < 4; ++jt32) {
        const int ch = jt32 * 4 + lq;
        half8 w2[4];
#pragma unroll
        for (int ntl = 0; ntl < 4; ++ntl)
            w2[ntl] = *(const half8*)((const char*)wsf + WS_W2F * 4
                                      + ((jt32 * 8 + nh * 4 + ntl) * 64 + ln) * 16);
#pragma unroll
        for (int s = 0; s < 2; ++s) {
            char* uvb = (char*)lds + L_UV * 4 + s * 16384;
            half8 u  = *(half8*)(uvb + ucol * 256 + ((ch ^ (ucol & 7)) << 4));
            half8 v0 = *(half8*)(uvb + 8192 + vcol0 * 256 + ((ch ^ (vcol0 & 7)) << 4));
            half8 v1 = *(half8*)(uvb + 8192 + vcol1 * 256 + ((ch ^ (vcol1 & 7)) << 4));
            half8 s0 = u + v0;
            half8 s1 = u + v1;
#if __has_builtin(__builtin_elementwise_max)
            half8 z = {};
            s0 = __builtin_elementwise_max(s0, z);
            s1 = __builtin_elementwise_max(s1, z);
#else
            us8 b0 = __builtin_bit_cast(us8, s0);
            us8 m0 = (b0 >> 15) - (us8)1; b0 &= m0;
            s0 = __builtin_bit_cast(half8, b0);
            us8 b1 = __builtin_bit_cast(us8, s1);
            us8 m1 = (b1 >> 15) - (us8)1; b1 &= m1;
            s1 = __builtin_bit_cast(half8, b1);
#endif
#pragma unroll
            for (int ntl = 0; ntl < 4; ++ntl) {
                acc2[s][0][ntl] = __builtin_amdgcn_mfma_f32_16x16x32_f16(w2[ntl], s0, acc2[s][0][ntl], 0, 0, 0);
                acc2[s][1][ntl] = __builtin_amdgcn_mfma_f32_16x16x32_f16(w2[ntl], s1, acc2[s][1][ntl], 0, 0, 0);
            }
        }
    }

    // ---- epilogue: relu * wc_eff (wc shared across s), shfl, partials to LDS ----
#pragma unroll
    for (int i = 0; i < 2; ++i) {
        const int pair = (rt0 + i) * 2 + (lr >> 3);
        const float* wcr = &wsf[pair * 128 + lq * 4];
        f32x4 wc[4];
#pragma unroll
        for (int ntl = 0; ntl < 4; ++ntl)
            wc[ntl] = *(const f32x4*)&wcr[(nh * 4 + ntl) * 16];
#pragma unroll
        for (int s = 0; s < 2; ++s) {
            float tot = 0.f;
#pragma unroll
            for (int ntl = 0; ntl < 4; ++ntl)
#pragma unroll
                for (int r2 = 0; r2 < 4; ++r2)
                    tot = fmaf(fmaxf(acc2[s][i][ntl][r2], 0.f), wc[ntl][r2], tot);
            tot += __shfl_xor(tot, 16, 64);
            tot += __shfl_xor(tot, 32, 64);
            if (lq == 0)
                lds[S_SP + s * 256 + nh * 128 + (rt0 + i) * 16 + lr] = tot;
        }
    }
    __syncthreads();

    if (t < 64) {
        const int s = t >> 5, tt = t & 31;
        const int r0 = tt * 4;
        float o = 0.f;
#pragma unroll
        for (int d = 0; d < 4; ++d) {
            const int r = r0 + d;
            o += fmaxf(lds[S_SP + s * 256 + r] + lds[S_SP + s * 256 + 128 + r] + bcv, 0.f);
        }
        out[(r0 >> 5) * 32768 + ((r0 >> 3) & 3) * 8192 + (bid * 2 + s) * 2 + ((r0 & 7) >> 2)] = o;
    }
}

extern "C" void kernel_launch(void* const* d_in, const int* in_sizes, int n_in,
                              void* d_out, int out_size, void* d_ws, size_t ws_size,
                              hipStream_t stream) {
    (void)in_sizes; (void)n_in; (void)out_size; (void)ws_size;
    const float* mc  = (const float*)d_in[0];
    const float* oh  = (const float*)d_in[1];
    const float* Wv  = (const float*)d_in[2];
    const float* bv  = (const float*)d_in[3];
    const float* Ws  = (const float*)d_in[4];
    const float* bs  = (const float*)d_in[5];
    const float* Wm  = (const float*)d_in[6];
    const float* bm  = (const float*)d_in[7];
    const float* rel = (const float*)d_in[8];
    const float* Wd1 = (const float*)d_in[9];
    const float* bd1 = (const float*)d_in[10];
    const float* Wd2 = (const float*)d_in[11];
    const float* bd2 = (const float*)d_in[12];
    const float* Wr1 = (const float*)d_in[13];
    const float* br1 = (const float*)d_in[14];
    const float* Wr2 = (const float*)d_in[15];
    const float* br2 = (const float*)d_in[16];
    const float* Wc  = (const float*)d_in[17];
    const float* bc  = (const float*)d_in[18];
    float* wsf = (float*)d_ws;
    float* out = (float*)d_out;

    hipLaunchKernelGGL(frap_setup, dim3(20), dim3(128), 0, stream,
                       Ws, bs, Wm, bm, rel, Wr1, br1, Wr2, br2, Wc, Wd1, Wd2, wsf);
    hipLaunchKernelGGL(frap_main, dim3(NBLK), dim3(NT), LDS_FLOATS * 4, stream,
                       mc, oh, Wv, bv, bd1, bd2, bc, wsf, out);
}